// Round 1
// baseline (315.489 us; speedup 1.0000x reference)
//
#include <hip/hip_runtime.h>
#include <hip/hip_bf16.h>

// KPConv on MI355X — Round 1: correct fp32 two-phase LDS-tiled kernel.
// B=2, N=16384, M=16384, K=32, C_IN=64, C_OUT=128, KS=15, sigma=0.05.
//
// Phase A (per block of TP=16 points): wave-per-point influence + F[j,c]
//   accumulation, F stored bf16 in LDS  [15][16][64].
// Phase B: per-j W tile (64x128 f32 = 32KB) staged in LDS (overlaid with
//   phase-A scratch), each thread accumulates 2 points x 4 outputs in fp32.

#define NB   16384
#define MB   16384
#define KN   32
#define CIN  64
#define COUT 128
#define KS   15
#define TP   16

__device__ __forceinline__ float blo(unsigned int u) { return __uint_as_float(u << 16); }
__device__ __forceinline__ float bhi(unsigned int u) { return __uint_as_float(u & 0xffff0000u); }

__device__ __forceinline__ unsigned short f32_to_bf16_rne(float x) {
    unsigned int u = __float_as_uint(x);
    unsigned int lsb = (u >> 16) & 1u;
    u += 0x7fffu + lsb;
    return (unsigned short)(u >> 16);
}

__global__ __launch_bounds__(256)
void kpconv_kernel(const float* __restrict__ qp,
                   const float* __restrict__ sp,
                   const float* __restrict__ feats,
                   const int* __restrict__ nidx,
                   const float* __restrict__ kp,
                   const float* __restrict__ Wg,
                   const float* __restrict__ bias,
                   float* __restrict__ out) {
    // LDS: [0,30720)        s_Fb  bf16 [KS][TP][CIN]
    //      [30720,63488)    phase A: infl [4][32][16] f32 (8 KB) + idx [4][32] (512 B)
    //                       phase B: W tile [64][128] f32 (32 KB)   (overlaid)
    __shared__ __align__(16) char smem[63488];
    unsigned short* s_Fb  = (unsigned short*)smem;
    float*          s_infl = (float*)(smem + 30720);
    int*            s_idx  = (int*)(smem + 30720 + 8192);
    float4*         s_W4   = (float4*)(smem + 30720);

    const int tid  = threadIdx.x;
    const int lane = tid & 63;
    const int wave = tid >> 6;
    const int gp_base = blockIdx.x * TP;
    const int b = gp_base >> 14;                 // / NB
    const size_t feat_base = (size_t)b * MB * CIN;
    const size_t sp_base   = (size_t)b * MB * 3;

    // ---------------- Phase A ----------------
    #pragma unroll 1
    for (int pt = 0; pt < 4; ++pt) {
        const int p  = wave * 4 + pt;
        const int gp = gp_base + p;

        if (lane < KN) {
            const int k   = lane;
            const int idx = nidx[gp * KN + k];
            const float qx = qp[gp * 3 + 0];
            const float qy = qp[gp * 3 + 1];
            const float qz = qp[gp * 3 + 2];
            const float* s3 = sp + sp_base + (size_t)idx * 3;
            const float rx = s3[0] - qx, ry = s3[1] - qy, rz = s3[2] - qz;
            float w[KS];
            float sum = 0.f;
            #pragma unroll
            for (int j = 0; j < KS; ++j) {
                const float dx = rx - kp[3 * j + 0];
                const float dy = ry - kp[3 * j + 1];
                const float dz = rz - kp[3 * j + 2];
                const float d2 = dx * dx + dy * dy + dz * dz;
                w[j] = __expf(-200.0f * d2);   // 1/(2*sigma^2) = 200
                sum += w[j];
            }
            const float inv = 1.0f / (sum + 1e-6f);
            float* si = s_infl + (wave * KN + k) * 16;
            #pragma unroll
            for (int j = 0; j < KS; ++j) si[j] = w[j] * inv;
            si[15] = 0.f;
            s_idx[wave * KN + k] = idx;
        }
        __syncthreads();

        // F[j] accumulation, lane = c
        float F[KS];
        #pragma unroll
        for (int j = 0; j < KS; ++j) F[j] = 0.f;
        const float* fb = feats + feat_base + lane;
        const float4* si4 = (const float4*)(s_infl + wave * KN * 16);
        #pragma unroll 4
        for (int k = 0; k < KN; ++k) {
            const int idx = s_idx[wave * KN + k];
            const float f = fb[(size_t)idx * CIN];
            const float4 i0 = si4[k * 4 + 0];
            const float4 i1 = si4[k * 4 + 1];
            const float4 i2 = si4[k * 4 + 2];
            const float4 i3 = si4[k * 4 + 3];
            F[0]  = fmaf(i0.x, f, F[0]);
            F[1]  = fmaf(i0.y, f, F[1]);
            F[2]  = fmaf(i0.z, f, F[2]);
            F[3]  = fmaf(i0.w, f, F[3]);
            F[4]  = fmaf(i1.x, f, F[4]);
            F[5]  = fmaf(i1.y, f, F[5]);
            F[6]  = fmaf(i1.z, f, F[6]);
            F[7]  = fmaf(i1.w, f, F[7]);
            F[8]  = fmaf(i2.x, f, F[8]);
            F[9]  = fmaf(i2.y, f, F[9]);
            F[10] = fmaf(i2.z, f, F[10]);
            F[11] = fmaf(i2.w, f, F[11]);
            F[12] = fmaf(i3.x, f, F[12]);
            F[13] = fmaf(i3.y, f, F[13]);
            F[14] = fmaf(i3.z, f, F[14]);
        }
        #pragma unroll
        for (int j = 0; j < KS; ++j) {
            s_Fb[(j * TP + p) * CIN + lane] = f32_to_bf16_rne(F[j]);
        }
    }
    __syncthreads();   // all F written before W tile overwrites scratch

    // ---------------- Phase B ----------------
    const int og = tid & 31;        // o = og*4 .. og*4+3
    const int ph = tid >> 5;        // 0..7
    const int p0 = ph, p1 = ph + 8;
    float4 acc0 = make_float4(0.f, 0.f, 0.f, 0.f);
    float4 acc1 = make_float4(0.f, 0.f, 0.f, 0.f);
    const float4* Wg4 = (const float4*)Wg;

    for (int j = 0; j < KS; ++j) {
        __syncthreads();            // previous tile's reads (or phase-A scratch) done
        #pragma unroll
        for (int r = 0; r < 8; ++r) {
            const int i4 = r * 256 + tid;
            s_W4[i4] = Wg4[(size_t)j * 2048 + i4];
        }
        __syncthreads();

        const unsigned short* f0p = s_Fb + (j * TP + p0) * CIN;
        const unsigned short* f1p = s_Fb + (j * TP + p1) * CIN;
        #pragma unroll 4
        for (int c4 = 0; c4 < 16; ++c4) {
            const uint2 u0 = *(const uint2*)(f0p + c4 * 4);
            const uint2 u1 = *(const uint2*)(f1p + c4 * 4);
            const float4 w0 = s_W4[(c4 * 4 + 0) * 32 + og];
            const float4 w1 = s_W4[(c4 * 4 + 1) * 32 + og];
            const float4 w2 = s_W4[(c4 * 4 + 2) * 32 + og];
            const float4 w3 = s_W4[(c4 * 4 + 3) * 32 + og];
            const float a0 = blo(u0.x), a1 = bhi(u0.x), a2 = blo(u0.y), a3 = bhi(u0.y);
            const float b0 = blo(u1.x), b1 = bhi(u1.x), b2 = blo(u1.y), b3 = bhi(u1.y);

            acc0.x = fmaf(a0, w0.x, acc0.x);
            acc0.x = fmaf(a1, w1.x, acc0.x);
            acc0.x = fmaf(a2, w2.x, acc0.x);
            acc0.x = fmaf(a3, w3.x, acc0.x);
            acc0.y = fmaf(a0, w0.y, acc0.y);
            acc0.y = fmaf(a1, w1.y, acc0.y);
            acc0.y = fmaf(a2, w2.y, acc0.y);
            acc0.y = fmaf(a3, w3.y, acc0.y);
            acc0.z = fmaf(a0, w0.z, acc0.z);
            acc0.z = fmaf(a1, w1.z, acc0.z);
            acc0.z = fmaf(a2, w2.z, acc0.z);
            acc0.z = fmaf(a3, w3.z, acc0.z);
            acc0.w = fmaf(a0, w0.w, acc0.w);
            acc0.w = fmaf(a1, w1.w, acc0.w);
            acc0.w = fmaf(a2, w2.w, acc0.w);
            acc0.w = fmaf(a3, w3.w, acc0.w);

            acc1.x = fmaf(b0, w0.x, acc1.x);
            acc1.x = fmaf(b1, w1.x, acc1.x);
            acc1.x = fmaf(b2, w2.x, acc1.x);
            acc1.x = fmaf(b3, w3.x, acc1.x);
            acc1.y = fmaf(b0, w0.y, acc1.y);
            acc1.y = fmaf(b1, w1.y, acc1.y);
            acc1.y = fmaf(b2, w2.y, acc1.y);
            acc1.y = fmaf(b3, w3.y, acc1.y);
            acc1.z = fmaf(b0, w0.z, acc1.z);
            acc1.z = fmaf(b1, w1.z, acc1.z);
            acc1.z = fmaf(b2, w2.z, acc1.z);
            acc1.z = fmaf(b3, w3.z, acc1.z);
            acc1.w = fmaf(b0, w0.w, acc1.w);
            acc1.w = fmaf(b1, w1.w, acc1.w);
            acc1.w = fmaf(b2, w2.w, acc1.w);
            acc1.w = fmaf(b3, w3.w, acc1.w);
        }
    }

    // epilogue: + bias, coalesced float4 stores
    const float4 bv = ((const float4*)bias)[og];
    float4 r0, r1;
    r0.x = acc0.x + bv.x; r0.y = acc0.y + bv.y; r0.z = acc0.z + bv.z; r0.w = acc0.w + bv.w;
    r1.x = acc1.x + bv.x; r1.y = acc1.y + bv.y; r1.z = acc1.z + bv.z; r1.w = acc1.w + bv.w;
    ((float4*)out)[(size_t)(gp_base + p0) * 32 + og] = r0;
    ((float4*)out)[(size_t)(gp_base + p1) * 32 + og] = r1;
}

extern "C" void kernel_launch(void* const* d_in, const int* in_sizes, int n_in,
                              void* d_out, int out_size, void* d_ws, size_t ws_size,
                              hipStream_t stream) {
    const float* qp = (const float*)d_in[0];   // query_points   [B,N,3]
    const float* sp = (const float*)d_in[1];   // support_points [B,M,3]
    const float* ft = (const float*)d_in[2];   // support_features [B,M,C_IN]
    const int*   ni = (const int*)d_in[3];     // neighbor_idx   [B,N,K]
    const float* kp = (const float*)d_in[4];   // kernel_points  [KS,3]
    const float* wg = (const float*)d_in[5];   // weights        [KS,C_IN,C_OUT]
    const float* bs = (const float*)d_in[6];   // bias           [C_OUT]
    float* o = (float*)d_out;                  // [B,N,C_OUT] fp32

    dim3 grid((NB * 2) / TP);   // 2048 blocks, 16 points each
    dim3 block(256);
    hipLaunchKernelGGL(kpconv_kernel, grid, block, 0, stream,
                       qp, sp, ft, ni, kp, wg, bs, o);
}

// Round 2
// 183.095 us; speedup vs baseline: 1.7231x; 1.7231x over previous
//
#include <hip/hip_runtime.h>
#include <hip/hip_bf16.h>

// KPConv MI355X — Round 2: MFMA phase B + readlane-broadcast phase A.
// B=2, N=16384, M=16384, K=32, C_IN=64, C_OUT=128, KS=15, sigma=0.05.
//
// Prepass: W fp32 [15][64][128] -> bf16 B-fragment layout in d_ws:
//   wfrag[s][t][lane][i] = W[k=s*32+(lane>>4)*8+i][n=t*16+(lane&15)], s<30,t<8.
// Main kernel, 1024 blocks x 256 thr, TP=32 points/block:
//   Phase A: per wave 4 pairs of points; lanes (half,k) compute influences in
//     registers; accumulation lane=c with v_readlane broadcast of idx/infl;
//     F written bf16 to LDS rows (stride 1936 B for even bank coverage).
//   Phase B: [32x960]@[960x128] GEMM, 16x16x32 bf16 MFMA, per wave
//     2 m-tiles x 2 n-tiles x 30 k-steps; B-frags straight from global (L2).

#define NB   16384
#define MB   16384
#define KN   32
#define CIN  64
#define COUT 128
#define KS   15
#define TP   32
#define FROW 1936      // F row stride in bytes (960*2 + 16 pad; /4 % 32 == 4)

typedef __attribute__((ext_vector_type(8))) short short8;
typedef __attribute__((ext_vector_type(4))) float f32x4;

static __device__ __forceinline__ unsigned short f32_to_bf16_rne(float x) {
    unsigned int u = __float_as_uint(x);
    unsigned int lsb = (u >> 16) & 1u;
    u += 0x7fffu + lsb;
    return (unsigned short)(u >> 16);
}

static __device__ __forceinline__ float rdlane_f(float v, int l) {
    return __int_as_float(__builtin_amdgcn_readlane(__float_as_int(v), l));
}

__global__ __launch_bounds__(256)
void wfrag_prep(const float* __restrict__ Wg, unsigned short* __restrict__ wf) {
    const int tid = blockIdx.x * 256 + threadIdx.x;
    if (tid >= 30 * 8 * 64) return;
    const int l = tid & 63;
    const int t = (tid >> 6) & 7;
    const int s = tid >> 9;
    const int n  = t * 16 + (l & 15);
    const int kb = s * 32 + (l >> 4) * 8;
    short8 o;
    #pragma unroll
    for (int i = 0; i < 8; ++i)
        o[i] = (short)f32_to_bf16_rne(Wg[(kb + i) * COUT + n]);
    *(short8*)(wf + (size_t)tid * 8) = o;
}

__global__ __launch_bounds__(256)
void kpconv_mfma(const float* __restrict__ qp,
                 const float* __restrict__ sp,
                 const float* __restrict__ feats,
                 const int* __restrict__ nidx,
                 const float* __restrict__ kp,
                 const unsigned short* __restrict__ wfrag,
                 const float* __restrict__ bias,
                 float* __restrict__ out) {
    __shared__ __align__(16) char sF[TP * FROW];   // 61952 B

    const int tid  = threadIdx.x;
    const int lane = tid & 63;
    const int wv   = tid >> 6;
    const int gp_base = blockIdx.x * TP;
    const int b = gp_base >> 14;
    const float* fb  = feats + (size_t)b * MB * CIN;
    const float* spb = sp + (size_t)b * MB * 3;

    // kernel points (uniform address -> scalar loads)
    float kx[KS], ky[KS], kz[KS];
    #pragma unroll
    for (int j = 0; j < KS; ++j) {
        kx[j] = kp[3 * j + 0];
        ky[j] = kp[3 * j + 1];
        kz[j] = kp[3 * j + 2];
    }

    // ---------------- Phase A ----------------
    #pragma unroll 1
    for (int pp = 0; pp < 4; ++pp) {
        const int pA = wv * 8 + pp * 2;           // block-local point pair base
        const int h  = lane >> 5;                 // which point of the pair
        const int k  = lane & 31;                 // neighbor index
        const int gpm = gp_base + pA + h;

        const int idxv = nidx[gpm * KN + k];
        const float qx = qp[gpm * 3 + 0];
        const float qy = qp[gpm * 3 + 1];
        const float qz = qp[gpm * 3 + 2];
        const float rx = spb[idxv * 3 + 0] - qx;
        const float ry = spb[idxv * 3 + 1] - qy;
        const float rz = spb[idxv * 3 + 2] - qz;

        float wn[KS];
        float ssum = 0.f;
        #pragma unroll
        for (int j = 0; j < KS; ++j) {
            const float dx = rx - kx[j];
            const float dy = ry - ky[j];
            const float dz = rz - kz[j];
            const float d2 = dx * dx + dy * dy + dz * dz;
            wn[j] = __expf(-200.0f * d2);         // 1/(2*sigma^2) = 200
            ssum += wn[j];
        }
        const float inv = 1.0f / (ssum + 1e-6f);
        #pragma unroll
        for (int j = 0; j < KS; ++j) wn[j] *= inv;

        // accumulation: lane = channel c; broadcast idx/infl via readlane
        float FA[KS], FB[KS];
        #pragma unroll
        for (int j = 0; j < KS; ++j) { FA[j] = 0.f; FB[j] = 0.f; }
        const int c = lane;
        #pragma unroll 4
        for (int kk = 0; kk < KN; ++kk) {
            const int ia = __builtin_amdgcn_readlane(idxv, kk);
            const int ib = __builtin_amdgcn_readlane(idxv, kk + 32);
            const float fav = fb[ia * CIN + c];
            const float fbv = fb[ib * CIN + c];
            #pragma unroll
            for (int j = 0; j < KS; ++j) {
                FA[j] = fmaf(rdlane_f(wn[j], kk),      fav, FA[j]);
                FB[j] = fmaf(rdlane_f(wn[j], kk + 32), fbv, FB[j]);
            }
        }

        unsigned short* r0 = (unsigned short*)(sF + (size_t)(pA    ) * FROW);
        unsigned short* r1 = (unsigned short*)(sF + (size_t)(pA + 1) * FROW);
        #pragma unroll
        for (int j = 0; j < KS; ++j) {
            r0[j * CIN + c] = f32_to_bf16_rne(FA[j]);
            r1[j * CIN + c] = f32_to_bf16_rne(FB[j]);
        }
    }
    __syncthreads();

    // ---------------- Phase B: MFMA ----------------
    const int lm = lane & 15, lq = lane >> 4;
    const int t0 = 2 * wv, t1 = 2 * wv + 1;
    f32x4 acc00 = {0.f, 0.f, 0.f, 0.f};
    f32x4 acc01 = {0.f, 0.f, 0.f, 0.f};
    f32x4 acc10 = {0.f, 0.f, 0.f, 0.f};
    f32x4 acc11 = {0.f, 0.f, 0.f, 0.f};

    const char* a0p = sF + lm * FROW + lq * 16;
    const char* a1p = a0p + 16 * FROW;

    #pragma unroll 2
    for (int s = 0; s < 30; ++s) {
        const short8 a0 = *(const short8*)(a0p + s * 64);
        const short8 a1 = *(const short8*)(a1p + s * 64);
        const short8 b0 = *(const short8*)(wfrag + ((size_t)(s * 8 + t0) * 64 + lane) * 8);
        const short8 b1 = *(const short8*)(wfrag + ((size_t)(s * 8 + t1) * 64 + lane) * 8);
        acc00 = __builtin_amdgcn_mfma_f32_16x16x32_bf16(a0, b0, acc00, 0, 0, 0);
        acc01 = __builtin_amdgcn_mfma_f32_16x16x32_bf16(a0, b1, acc01, 0, 0, 0);
        acc10 = __builtin_amdgcn_mfma_f32_16x16x32_bf16(a1, b0, acc10, 0, 0, 0);
        acc11 = __builtin_amdgcn_mfma_f32_16x16x32_bf16(a1, b1, acc11, 0, 0, 0);
    }

    const float bs0 = bias[t0 * 16 + lm];
    const float bs1 = bias[t1 * 16 + lm];
    #pragma unroll
    for (int r = 0; r < 4; ++r) {
        const int pr0 = lq * 4 + r;        // m-tile 0 rows
        const int pr1 = 16 + pr0;          // m-tile 1 rows
        out[(size_t)(gp_base + pr0) * COUT + t0 * 16 + lm] = acc00[r] + bs0;
        out[(size_t)(gp_base + pr0) * COUT + t1 * 16 + lm] = acc01[r] + bs1;
        out[(size_t)(gp_base + pr1) * COUT + t0 * 16 + lm] = acc10[r] + bs0;
        out[(size_t)(gp_base + pr1) * COUT + t1 * 16 + lm] = acc11[r] + bs1;
    }
}

extern "C" void kernel_launch(void* const* d_in, const int* in_sizes, int n_in,
                              void* d_out, int out_size, void* d_ws, size_t ws_size,
                              hipStream_t stream) {
    const float* qp = (const float*)d_in[0];   // query_points   [B,N,3]
    const float* sp = (const float*)d_in[1];   // support_points [B,M,3]
    const float* ft = (const float*)d_in[2];   // support_features [B,M,C_IN]
    const int*   ni = (const int*)d_in[3];     // neighbor_idx   [B,N,K]
    const float* kp = (const float*)d_in[4];   // kernel_points  [KS,3]
    const float* wg = (const float*)d_in[5];   // weights        [KS,C_IN,C_OUT]
    const float* bs = (const float*)d_in[6];   // bias           [C_OUT]
    float* o = (float*)d_out;                  // [B,N,C_OUT] fp32

    unsigned short* wfrag = (unsigned short*)d_ws;   // 245760 B needed

    hipLaunchKernelGGL(wfrag_prep, dim3(60), dim3(256), 0, stream, wg, wfrag);
    hipLaunchKernelGGL(kpconv_mfma, dim3((2 * NB) / TP), dim3(256), 0, stream,
                       qp, sp, ft, ni, kp, wfrag, bs, o);
}

// Round 3
// 130.739 us; speedup vs baseline: 2.4131x; 1.4005x over previous
//
#include <hip/hip_runtime.h>
#include <hip/hip_bf16.h>

// KPConv MI355X — Round 3: MFMA for BOTH phases.
// B=2, N=16384, M=16384, K=32, C_IN=64, C_OUT=128, KS=15, sigma=0.05.
//
// Phase A (per wave, per point): F[j,c] = sum_k infl[k,j] * feat[idx[k],c]
//   as one 16x16x32 bf16 MFMA M-tile x 4 N-tiles.
//   Lane (j=lane&15, quad=lane>>4): influences computed straight into
//   A-frag layout (k = quad*8+i), j==15 zero pad; sum_j via shfl_xor w16;
//   B-frag = gathered feats (same quad/idx decomposition). D -> bf16 -> LDS.
// Phase B (per block): [32 x 960] @ [960 x 128] bf16 MFMA GEMM, W B-frags
//   straight from L2 (prepass-packed in d_ws).

#define NB   16384
#define MB   16384
#define KN   32
#define CIN  64
#define COUT 128
#define KS   15
#define TP   32
#define FROW 1936      // F row stride bytes (960*2 + 16 pad; /4 % 32 == 4)

typedef __attribute__((ext_vector_type(8))) short short8;
typedef __attribute__((ext_vector_type(4))) float f32x4;

static __device__ __forceinline__ unsigned short f32_to_bf16_rne(float x) {
    unsigned int u = __float_as_uint(x);
    unsigned int lsb = (u >> 16) & 1u;
    u += 0x7fffu + lsb;
    return (unsigned short)(u >> 16);
}

__global__ __launch_bounds__(256)
void wfrag_prep(const float* __restrict__ Wg, unsigned short* __restrict__ wf) {
    const int tid = blockIdx.x * 256 + threadIdx.x;
    if (tid >= 30 * 8 * 64) return;
    const int l = tid & 63;
    const int t = (tid >> 6) & 7;
    const int s = tid >> 9;
    const int n  = t * 16 + (l & 15);
    const int kb = s * 32 + (l >> 4) * 8;
    short8 o;
    #pragma unroll
    for (int i = 0; i < 8; ++i)
        o[i] = (short)f32_to_bf16_rne(Wg[(kb + i) * COUT + n]);
    *(short8*)(wf + (size_t)tid * 8) = o;
}

__global__ __launch_bounds__(256)
void kpconv_mfma(const float* __restrict__ qp,
                 const float* __restrict__ sp,
                 const float* __restrict__ feats,
                 const int* __restrict__ nidx,
                 const float* __restrict__ kp,
                 const unsigned short* __restrict__ wfrag,
                 const float* __restrict__ bias,
                 float* __restrict__ out) {
    __shared__ __align__(16) char sF[TP * FROW];   // 61952 B

    const int tid  = threadIdx.x;
    const int lane = tid & 63;
    const int wv   = tid >> 6;
    const int gp_base = blockIdx.x * TP;
    const int b = gp_base >> 14;
    const float* fb  = feats + (size_t)b * MB * CIN;
    const float* spb = sp + (size_t)b * MB * 3;

    const int n16  = lane & 15;     // j (influence / A-row) and n (feat col)
    const int quad = lane >> 4;     // k-group selector for both operands

    // kernel point for this lane's j (clamped; j==15 is zero pad anyway)
    const int jc = n16 < 14 ? n16 : 14;
    const float kxj = kp[3 * jc + 0];
    const float kyj = kp[3 * jc + 1];
    const float kzj = kp[3 * jc + 2];

    // ---------------- Phase A: per-point MFMA ----------------
    #pragma unroll 1
    for (int pt = 0; pt < 8; ++pt) {
        const int pl = wv * 8 + pt;            // block-local point
        const int gp = gp_base + pl;

        // 8 neighbor indices for this quad (broadcast across 16 lanes)
        const int* ip = nidx + (size_t)gp * KN + quad * 8;
        int idxv[8];
        *(int4*)(&idxv[0]) = *(const int4*)(ip);
        *(int4*)(&idxv[4]) = *(const int4*)(ip + 4);

        const float qx = qp[3 * gp + 0];
        const float qy = qp[3 * gp + 1];
        const float qz = qp[3 * gp + 2];
        const float qkx = qx + kxj, qky = qy + kyj, qkz = qz + kzj;

        // influences in A-frag layout: e[i] = infl[k=quad*8+i][j=n16]
        float e[8];
        #pragma unroll
        for (int i = 0; i < 8; ++i) {
            const float* s3 = spb + (size_t)idxv[i] * 3;
            const float dx = s3[0] - qkx;
            const float dy = s3[1] - qky;
            const float dz = s3[2] - qkz;
            const float d2 = fmaf(dx, dx, fmaf(dy, dy, dz * dz));
            float ev = __expf(-200.0f * d2);   // 1/(2*sigma^2) = 200
            e[i] = (n16 < 15) ? ev : 0.0f;     // zero pad row j=15
        }

        // normalize: sum over j = 16 lanes of this quad-group
        short8 afrag;
        #pragma unroll
        for (int i = 0; i < 8; ++i) {
            float s = e[i];
            s += __shfl_xor(s, 1, 16);
            s += __shfl_xor(s, 2, 16);
            s += __shfl_xor(s, 4, 16);
            s += __shfl_xor(s, 8, 16);
            const float inv = __builtin_amdgcn_rcpf(s + 1e-6f);
            afrag[i] = (short)f32_to_bf16_rne(e[i] * inv);
        }

        // B-frags: gathered feats, lane holds feat[idx[quad*8+i]][t*16+n16]
        short8 bfr[4];
        #pragma unroll
        for (int i = 0; i < 8; ++i) {
            const float* fr = fb + (size_t)idxv[i] * CIN + n16;
            #pragma unroll
            for (int t = 0; t < 4; ++t)
                bfr[t][i] = (short)f32_to_bf16_rne(fr[t * 16]);
        }

        // 4 MFMAs: D[j][c] per n-tile
        f32x4 dd[4];
        #pragma unroll
        for (int t = 0; t < 4; ++t) {
            f32x4 z = {0.f, 0.f, 0.f, 0.f};
            dd[t] = __builtin_amdgcn_mfma_f32_16x16x32_bf16(afrag, bfr[t], z, 0, 0, 0);
        }

        // store F bf16: C-layout lane holds D[j=quad*4+r][c=t*16+n16]
        unsigned short* fp_ = (unsigned short*)(sF + (size_t)pl * FROW);
        #pragma unroll
        for (int t = 0; t < 4; ++t) {
            #pragma unroll
            for (int r = 0; r < 4; ++r) {
                const int jr = quad * 4 + r;
                if (jr < 15)
                    fp_[jr * CIN + t * 16 + n16] = f32_to_bf16_rne(dd[t][r]);
            }
        }
    }
    __syncthreads();

    // ---------------- Phase B: block GEMM via MFMA ----------------
    const int lm = lane & 15, lq = lane >> 4;
    const int t0 = 2 * wv, t1 = 2 * wv + 1;
    f32x4 acc00 = {0.f, 0.f, 0.f, 0.f};
    f32x4 acc01 = {0.f, 0.f, 0.f, 0.f};
    f32x4 acc10 = {0.f, 0.f, 0.f, 0.f};
    f32x4 acc11 = {0.f, 0.f, 0.f, 0.f};

    const char* a0p = sF + lm * FROW + lq * 16;
    const char* a1p = a0p + 16 * FROW;

    #pragma unroll 2
    for (int s = 0; s < 30; ++s) {
        const short8 a0 = *(const short8*)(a0p + s * 64);
        const short8 a1 = *(const short8*)(a1p + s * 64);
        const short8 b0 = *(const short8*)(wfrag + ((size_t)(s * 8 + t0) * 64 + lane) * 8);
        const short8 b1 = *(const short8*)(wfrag + ((size_t)(s * 8 + t1) * 64 + lane) * 8);
        acc00 = __builtin_amdgcn_mfma_f32_16x16x32_bf16(a0, b0, acc00, 0, 0, 0);
        acc01 = __builtin_amdgcn_mfma_f32_16x16x32_bf16(a0, b1, acc01, 0, 0, 0);
        acc10 = __builtin_amdgcn_mfma_f32_16x16x32_bf16(a1, b0, acc10, 0, 0, 0);
        acc11 = __builtin_amdgcn_mfma_f32_16x16x32_bf16(a1, b1, acc11, 0, 0, 0);
    }

    const float bs0 = bias[t0 * 16 + lm];
    const float bs1 = bias[t1 * 16 + lm];
    #pragma unroll
    for (int r = 0; r < 4; ++r) {
        const int pr0 = lq * 4 + r;
        const int pr1 = 16 + pr0;
        out[(size_t)(gp_base + pr0) * COUT + t0 * 16 + lm] = acc00[r] + bs0;
        out[(size_t)(gp_base + pr0) * COUT + t1 * 16 + lm] = acc01[r] + bs1;
        out[(size_t)(gp_base + pr1) * COUT + t0 * 16 + lm] = acc10[r] + bs0;
        out[(size_t)(gp_base + pr1) * COUT + t1 * 16 + lm] = acc11[r] + bs1;
    }
}

extern "C" void kernel_launch(void* const* d_in, const int* in_sizes, int n_in,
                              void* d_out, int out_size, void* d_ws, size_t ws_size,
                              hipStream_t stream) {
    const float* qp = (const float*)d_in[0];   // query_points   [B,N,3]
    const float* sp = (const float*)d_in[1];   // support_points [B,M,3]
    const float* ft = (const float*)d_in[2];   // support_features [B,M,C_IN]
    const int*   ni = (const int*)d_in[3];     // neighbor_idx   [B,N,K]
    const float* kp = (const float*)d_in[4];   // kernel_points  [KS,3]
    const float* wg = (const float*)d_in[5];   // weights        [KS,C_IN,C_OUT]
    const float* bs = (const float*)d_in[6];   // bias           [C_OUT]
    float* o = (float*)d_out;                  // [B,N,C_OUT] fp32

    unsigned short* wfrag = (unsigned short*)d_ws;   // 245760 B needed

    hipLaunchKernelGGL(wfrag_prep, dim3(60), dim3(256), 0, stream, wg, wfrag);
    hipLaunchKernelGGL(kpconv_mfma, dim3((2 * NB) / TP), dim3(256), 0, stream,
                       qp, sp, ft, ni, kp, wfrag, bs, o);
}

// Round 4
// 112.553 us; speedup vs baseline: 2.8030x; 1.1616x over previous
//
#include <hip/hip_runtime.h>
#include <hip/hip_bf16.h>

// KPConv MI355X — Round 4: occupancy (512-thr blocks, 16 waves/CU) +
// operand-swapped phase-A MFMA with b64 swizzled F-stores + bf16 feats.
// B=2, N=16384, M=16384, K=32, C_IN=64, C_OUT=128, KS=15, sigma=0.05.
//
// Prep kernel: (a) W fp32 -> bf16 B-frag layout in d_ws (as R2/R3);
//              (b) feats fp32 -> bf16 flat [B*M][64] at d_ws+245760 (if room).
// Main kernel: 1024 blocks x 512 thr, TP=32 points.
//   Phase A (wave = 4 points): influences in B-frag layout (j=lane&15,
//     k=quad*8+i), feats gathered in A-frag layout; D = F[c][j] per m-tile,
//     stored to LDS as bf16 with XOR-(j&7)<<4 chunk swizzle, ds_write_b64.
//   Phase B: [32 x 960] @ [960 x 128] bf16 MFMA; wave wv owns n-tile wv,
//     both m-tiles; W B-frags straight from L2 (packed); 1 barrier total.

#define NB   16384
#define MB   16384
#define KN   32
#define CIN  64
#define COUT 128
#define KS   15
#define TP   32
#define PROW 2064            // LDS bytes per point row (16*128 + 16; /4 % 32 == 4)
#define WFRAG_BYTES 245760u
#define F16_BYTES   (2u * MB * CIN * 2u)   // 4,194,304

typedef __attribute__((ext_vector_type(8))) short short8;
typedef __attribute__((ext_vector_type(4))) float f32x4;

// round-to-nearest (ties-away) bf16 pack: low short = f0, high short = f1
static __device__ __forceinline__ unsigned int pack2_bf16(float f0, float f1) {
    const unsigned int a = __float_as_uint(f0) + 0x8000u;
    const unsigned int b = __float_as_uint(f1) + 0x8000u;
    return (a >> 16) | (b & 0xffff0000u);
}

// RNE bf16 pack (for weight/feat prepass — matches prior rounds' accuracy)
static __device__ __forceinline__ unsigned int pack2_bf16_rne(float f0, float f1) {
    unsigned int a = __float_as_uint(f0);
    unsigned int b = __float_as_uint(f1);
    a += 0x7fffu + ((a >> 16) & 1u);
    b += 0x7fffu + ((b >> 16) & 1u);
    return (a >> 16) | (b & 0xffff0000u);
}

static __device__ __forceinline__ unsigned short f32_to_bf16_rne(float x) {
    unsigned int u = __float_as_uint(x);
    u += 0x7fffu + ((u >> 16) & 1u);
    return (unsigned short)(u >> 16);
}

__global__ __launch_bounds__(256)
void prep_kernel(const float* __restrict__ Wg, const float* __restrict__ feats,
                 unsigned short* __restrict__ wf, unsigned int* __restrict__ f16,
                 int do_feats) {
    const int bid = blockIdx.x;
    if (bid < 60) {
        const int tid = bid * 256 + threadIdx.x;   // < 15360 exactly
        const int l = tid & 63;
        const int t = (tid >> 6) & 7;
        const int s = tid >> 9;
        const int n  = t * 16 + (l & 15);
        const int kb = s * 32 + (l >> 4) * 8;
        short8 o;
        #pragma unroll
        for (int i = 0; i < 8; ++i)
            o[i] = (short)f32_to_bf16_rne(Wg[(kb + i) * COUT + n]);
        *(short8*)(wf + (size_t)tid * 8) = o;
    } else if (do_feats) {
        const unsigned int t = (unsigned int)(bid - 60) * 256u + threadIdx.x;
        if (t < 2u * MB * CIN / 2u) {
            const float2 v = ((const float2*)feats)[t];
            f16[t] = pack2_bf16_rne(v.x, v.y);
        }
    }
}

template<bool F16>
__global__ __launch_bounds__(512, 4)
void kpconv_mfma(const float* __restrict__ qp,
                 const float* __restrict__ sp,
                 const float* __restrict__ feats,
                 const unsigned short* __restrict__ fbh16,
                 const int* __restrict__ nidx,
                 const float* __restrict__ kp,
                 const unsigned short* __restrict__ wfrag,
                 const float* __restrict__ bias,
                 float* __restrict__ out) {
    __shared__ __align__(16) char sF[TP * PROW];   // 66048 B -> 2 blocks/CU

    const int tid  = threadIdx.x;
    const int lane = tid & 63;
    const int wv   = tid >> 6;                 // 0..7
    const int gp_base = blockIdx.x * TP;
    const int b = gp_base >> 14;
    const float*          fbf = feats + (size_t)b * MB * CIN;
    const unsigned short* fbh = fbh16 + (size_t)b * MB * CIN;
    const float*          spb = sp + (size_t)b * MB * 3;

    const int n16  = lane & 15;     // j (influence col) / c-sub (feat col)
    const int quad = lane >> 4;     // k-group selector

    const int jc = n16 < 14 ? n16 : 14;
    const float kxj = kp[3 * jc + 0];
    const float kyj = kp[3 * jc + 1];
    const float kzj = kp[3 * jc + 2];

    // ---------------- Phase A: 4 points per wave ----------------
    #pragma unroll 1
    for (int pt = 0; pt < 4; ++pt) {
        const int pl = wv * 4 + pt;
        const int gp = gp_base + pl;

        const int* ip = nidx + (size_t)gp * KN + quad * 8;
        int idxv[8];
        *(int4*)(&idxv[0]) = *(const int4*)(ip);
        *(int4*)(&idxv[4]) = *(const int4*)(ip + 4);

        const float qx = qp[3 * gp + 0];
        const float qy = qp[3 * gp + 1];
        const float qz = qp[3 * gp + 2];
        const float qkx = qx + kxj, qky = qy + kyj, qkz = qz + kzj;

        // influences, B-frag layout: elem i = infl[k=quad*8+i][j=n16]
        float e[8];
        #pragma unroll
        for (int i = 0; i < 8; ++i) {
            const float* s3 = spb + (size_t)idxv[i] * 3;
            const float dx = s3[0] - qkx;
            const float dy = s3[1] - qky;
            const float dz = s3[2] - qkz;
            const float d2 = fmaf(dx, dx, fmaf(dy, dy, dz * dz));
            const float ev = __expf(-200.0f * d2);   // 1/(2*sigma^2)
            e[i] = (n16 < 15) ? ev : 0.0f;           // zero col j=15
        }

        unsigned int iu[4];
        float en[8];
        #pragma unroll
        for (int i = 0; i < 8; ++i) {
            float s = e[i];
            s += __shfl_xor(s, 1, 16);
            s += __shfl_xor(s, 2, 16);
            s += __shfl_xor(s, 4, 16);
            s += __shfl_xor(s, 8, 16);
            en[i] = e[i] * __builtin_amdgcn_rcpf(s + 1e-6f);
        }
        #pragma unroll
        for (int ih = 0; ih < 4; ++ih)
            iu[ih] = pack2_bf16(en[2 * ih], en[2 * ih + 1]);
        const short8 ifrag = *(const short8*)iu;

        // feats, A-frag layout: elem i = feat[idx[quad*8+i]][c=t*16+n16]
        unsigned int fu[4][4];
        #pragma unroll
        for (int ih = 0; ih < 4; ++ih) {
            if (F16) {
                const unsigned short* fr0 = fbh + (size_t)idxv[2 * ih]     * CIN + n16;
                const unsigned short* fr1 = fbh + (size_t)idxv[2 * ih + 1] * CIN + n16;
                #pragma unroll
                for (int t = 0; t < 4; ++t) {
                    const unsigned int lo = fr0[t * 16];
                    const unsigned int hi = fr1[t * 16];
                    fu[t][ih] = lo | (hi << 16);
                }
            } else {
                const float* fr0 = fbf + (size_t)idxv[2 * ih]     * CIN + n16;
                const float* fr1 = fbf + (size_t)idxv[2 * ih + 1] * CIN + n16;
                #pragma unroll
                for (int t = 0; t < 4; ++t)
                    fu[t][ih] = pack2_bf16(fr0[t * 16], fr1[t * 16]);
            }
        }

        // D[c_local][j] per m-tile t; store F[j][c] bf16 with XOR swizzle
        #pragma unroll
        for (int t = 0; t < 4; ++t) {
            const short8 ffrag = *(const short8*)(fu[t]);
            f32x4 z = {0.f, 0.f, 0.f, 0.f};
            const f32x4 dd = __builtin_amdgcn_mfma_f32_16x16x32_bf16(ffrag, ifrag, z, 0, 0, 0);
            const unsigned int lo = pack2_bf16(dd[0], dd[1]);
            const unsigned int hi = pack2_bf16(dd[2], dd[3]);
            const int off = pl * PROW + n16 * 128 +
                            ((t * 32 + quad * 8) ^ ((n16 & 7) << 4));
            uint2 v; v.x = lo; v.y = hi;
            *(uint2*)(sF + off) = v;                  // ds_write_b64
        }
    }
    __syncthreads();

    // ---------------- Phase B: wave wv owns n-tile wv, both m-tiles ----------------
    const int lm = n16;                               // point within m-tile
    f32x4 acc0 = {0.f, 0.f, 0.f, 0.f};
    f32x4 acc1 = {0.f, 0.f, 0.f, 0.f};
    const char* aBase = sF + lm * PROW;

    #pragma unroll
    for (int s = 0; s < 30; ++s) {
        const int j   = s >> 1;
        const int c0b = (s & 1) * 64 + quad * 16;
        const int off = j * 128 + (c0b ^ ((j & 7) << 4));
        const short8 a0 = *(const short8*)(aBase + off);
        const short8 a1 = *(const short8*)(aBase + 16 * PROW + off);
        const short8 bf = *(const short8*)(wfrag + ((size_t)(s * 8 + wv) * 64 + lane) * 8);
        acc0 = __builtin_amdgcn_mfma_f32_16x16x32_bf16(a0, bf, acc0, 0, 0, 0);
        acc1 = __builtin_amdgcn_mfma_f32_16x16x32_bf16(a1, bf, acc1, 0, 0, 0);
    }

    const float bsv = bias[wv * 16 + lm];
    #pragma unroll
    for (int r = 0; r < 4; ++r) {
        const int pr = quad * 4 + r;
        out[(size_t)(gp_base + pr)      * COUT + wv * 16 + lm] = acc0[r] + bsv;
        out[(size_t)(gp_base + 16 + pr) * COUT + wv * 16 + lm] = acc1[r] + bsv;
    }
}

extern "C" void kernel_launch(void* const* d_in, const int* in_sizes, int n_in,
                              void* d_out, int out_size, void* d_ws, size_t ws_size,
                              hipStream_t stream) {
    const float* qp = (const float*)d_in[0];   // query_points   [B,N,3]
    const float* sp = (const float*)d_in[1];   // support_points [B,M,3]
    const float* ft = (const float*)d_in[2];   // support_features [B,M,C_IN]
    const int*   ni = (const int*)d_in[3];     // neighbor_idx   [B,N,K]
    const float* kp = (const float*)d_in[4];   // kernel_points  [KS,3]
    const float* wg = (const float*)d_in[5];   // weights        [KS,C_IN,C_OUT]
    const float* bs = (const float*)d_in[6];   // bias           [C_OUT]
    float* o = (float*)d_out;                  // [B,N,C_OUT] fp32

    unsigned short* wfrag = (unsigned short*)d_ws;
    unsigned int*   f16   = (unsigned int*)((char*)d_ws + WFRAG_BYTES);
    const int do_feats = (ws_size >= (size_t)WFRAG_BYTES + F16_BYTES) ? 1 : 0;

    const int prep_blocks = do_feats ? (60 + 4096) : 60;
    hipLaunchKernelGGL(prep_kernel, dim3(prep_blocks), dim3(256), 0, stream,
                       wg, ft, wfrag, f16, do_feats);

    if (do_feats) {
        hipLaunchKernelGGL((kpconv_mfma<true>), dim3((2 * NB) / TP), dim3(512), 0, stream,
                           qp, sp, ft, (const unsigned short*)f16, ni, kp, wfrag, bs, o);
    } else {
        hipLaunchKernelGGL((kpconv_mfma<false>), dim3((2 * NB) / TP), dim3(512), 0, stream,
                           qp, sp, ft, (const unsigned short*)f16, ni, kp, wfrag, bs, o);
    }
}

// Round 5
// 111.595 us; speedup vs baseline: 2.8271x; 1.0086x over previous
//
#include <hip/hip_runtime.h>
#include <hip/hip_bf16.h>

// KPConv MI355X — Round 5: cut phase-A VMEM instruction count.
// B=2, N=16384, M=16384, K=32, C_IN=64, C_OUT=128, KS=15, sigma=0.05.
//
// Prepass packs into d_ws:
//   [0)        W bf16 B-frag layout (245760 B)   (as R2..R4)
//   [245760)   feats bf16 PERMUTED: row m holds channel c=t*16+n16 at
//              position n16*4+t  -> lane's 4 channels = one 8-B load
//   [4440064)  support_points as float4 (x,y,z,0) -> one dwordx4/neighbor
// Main kernel: 1024 blocks x 512 thr, TP=32 points, LDS 66048 B (2 blk/CU).
//   Phase A (wave = 4 points, idx prefetched 1 point ahead):
//     influences in B-frag layout (j=lane&15, k=quad*8+i), feats gathered
//     as uint2 + v_perm repack into A-frags; D=F[c][j]; bf16 -> LDS with
//     XOR-(j&7)<<4 chunk swizzle, ds_write_b64.
//   Phase B: [32x960]@[960x128] bf16 MFMA; wave wv owns n-tile wv, both
//     m-tiles; W B-frags straight from L2; 1 barrier total.

#define NB   16384
#define MB   16384
#define KN   32
#define CIN  64
#define COUT 128
#define KS   15
#define TP   32
#define PROW 2064            // LDS bytes per point row (16*128 + 16; /4 % 32 == 4)
#define WF_BYTES  245760u
#define FP_BYTES  (2u * MB * CIN * 2u)    // 4,194,304
#define SP4_BYTES (2u * MB * 16u)         //   524,288

typedef __attribute__((ext_vector_type(8))) short short8;
typedef __attribute__((ext_vector_type(4))) float f32x4;

// round-to-nearest (ties-away) bf16 pack: low short = f0, high short = f1
static __device__ __forceinline__ unsigned int pack2_bf16(float f0, float f1) {
    const unsigned int a = __float_as_uint(f0) + 0x8000u;
    const unsigned int b = __float_as_uint(f1) + 0x8000u;
    return (a >> 16) | (b & 0xffff0000u);
}

static __device__ __forceinline__ unsigned int pack2_bf16_rne(float f0, float f1) {
    unsigned int a = __float_as_uint(f0);
    unsigned int b = __float_as_uint(f1);
    a += 0x7fffu + ((a >> 16) & 1u);
    b += 0x7fffu + ((b >> 16) & 1u);
    return (a >> 16) | (b & 0xffff0000u);
}

static __device__ __forceinline__ unsigned short f32_to_bf16_rne(float x) {
    unsigned int u = __float_as_uint(x);
    u += 0x7fffu + ((u >> 16) & 1u);
    return (unsigned short)(u >> 16);
}

__global__ __launch_bounds__(256)
void prep_kernel(const float* __restrict__ Wg, const float* __restrict__ feats,
                 const float* __restrict__ sp,
                 unsigned short* __restrict__ wf, unsigned int* __restrict__ fp,
                 float4* __restrict__ sp4, int full) {
    const int bid = blockIdx.x;
    if (bid < 60) {
        // W -> bf16 B-frag layout (15360 threads exactly)
        const int tid = bid * 256 + threadIdx.x;
        const int l = tid & 63;
        const int t = (tid >> 6) & 7;
        const int s = tid >> 9;
        const int n  = t * 16 + (l & 15);
        const int kb = s * 32 + (l >> 4) * 8;
        short8 o;
        #pragma unroll
        for (int i = 0; i < 8; ++i)
            o[i] = (short)f32_to_bf16_rne(Wg[(kb + i) * COUT + n]);
        *(short8*)(wf + (size_t)tid * 8) = o;
    } else if (!full) {
        return;
    } else if (bid < 60 + 128) {
        // support points -> float4 (32768 threads exactly)
        const int m = (bid - 60) * 256 + threadIdx.x;
        const float* s3 = sp + 3 * (size_t)m;
        sp4[m] = make_float4(s3[0], s3[1], s3[2], 0.0f);
    } else {
        // feats -> bf16 permuted: row m, position p=n16*4+t holds c=t*16+n16
        const unsigned int t = (unsigned int)(bid - 188) * 256u + threadIdx.x;
        if (t < 2u * MB * 32u) {          // u32 outputs: 32 per row
            const int m   = t >> 5;
            const int p2  = t & 31;       // output u32 = positions 2p2,2p2+1
            const int n16 = p2 >> 1;
            const int tt  = (p2 & 1) * 2;
            const float a = feats[(size_t)m * CIN + tt * 16 + n16];
            const float b = feats[(size_t)m * CIN + (tt + 1) * 16 + n16];
            fp[t] = pack2_bf16_rne(a, b);
        }
    }
}

template<bool PK>
__global__ __launch_bounds__(512, 4)
void kpconv_mfma(const float* __restrict__ qp,
                 const float* __restrict__ sp,
                 const float* __restrict__ feats,
                 const unsigned int* __restrict__ fpk,
                 const float4* __restrict__ sp4,
                 const int* __restrict__ nidx,
                 const float* __restrict__ kp,
                 const unsigned short* __restrict__ wfrag,
                 const float* __restrict__ bias,
                 float* __restrict__ out) {
    __shared__ __align__(16) char sF[TP * PROW];   // 66048 B -> 2 blocks/CU

    const int tid  = threadIdx.x;
    const int lane = tid & 63;
    const int wv   = tid >> 6;                 // 0..7
    const int gp_base = blockIdx.x * TP;
    const int b = gp_base >> 14;
    const float*        fbf  = feats + (size_t)b * MB * CIN;
    const unsigned int* fpb  = fpk + (size_t)b * MB * 32;       // 32 u32/row
    const float4*       sp4b = sp4 + (size_t)b * MB;
    const float*        spb  = sp + (size_t)b * MB * 3;

    const int n16  = lane & 15;     // j (influence col) / c-sub (feat row sel)
    const int quad = lane >> 4;     // k-group selector

    const int jc = n16 < 14 ? n16 : 14;
    const float kxj = kp[3 * jc + 0];
    const float kyj = kp[3 * jc + 1];
    const float kzj = kp[3 * jc + 2];

    // ---------------- Phase A: 4 points per wave, idx prefetch ----------------
    const int gp0 = gp_base + wv * 4;
    const int* ip = nidx + (size_t)gp0 * KN + quad * 8;
    int4 nx0 = *(const int4*)(ip);
    int4 nx1 = *(const int4*)(ip + 4);

    #pragma unroll 1
    for (int pt = 0; pt < 4; ++pt) {
        const int pl = wv * 4 + pt;
        const int gp = gp0 + pt;

        int idxv[8];
        *(int4*)(&idxv[0]) = nx0;
        *(int4*)(&idxv[4]) = nx1;
        if (pt < 3) {
            const int* ipn = ip + (pt + 1) * KN;
            nx0 = *(const int4*)(ipn);
            nx1 = *(const int4*)(ipn + 4);
        }

        const float qx = qp[3 * gp + 0];
        const float qy = qp[3 * gp + 1];
        const float qz = qp[3 * gp + 2];
        const float qkx = qx + kxj, qky = qy + kyj, qkz = qz + kzj;

        // gather loads (issued together): sp4 dwordx4 + feats uint2
        float e[8];
        uint2 g[8];
        if (PK) {
            float4 s4[8];
            #pragma unroll
            for (int i = 0; i < 8; ++i) s4[i] = sp4b[idxv[i]];
            #pragma unroll
            for (int i = 0; i < 8; ++i)
                g[i] = *(const uint2*)(fpb + (size_t)idxv[i] * 32 + n16 * 2);
            #pragma unroll
            for (int i = 0; i < 8; ++i) {
                const float dx = s4[i].x - qkx;
                const float dy = s4[i].y - qky;
                const float dz = s4[i].z - qkz;
                const float d2 = fmaf(dx, dx, fmaf(dy, dy, dz * dz));
                const float ev = __expf(-200.0f * d2);   // 1/(2*sigma^2)
                e[i] = (n16 < 15) ? ev : 0.0f;           // zero col j=15
            }
        } else {
            #pragma unroll
            for (int i = 0; i < 8; ++i) {
                const float* s3 = spb + (size_t)idxv[i] * 3;
                const float dx = s3[0] - qkx;
                const float dy = s3[1] - qky;
                const float dz = s3[2] - qkz;
                const float d2 = fmaf(dx, dx, fmaf(dy, dy, dz * dz));
                const float ev = __expf(-200.0f * d2);
                e[i] = (n16 < 15) ? ev : 0.0f;
            }
        }

        // normalize over j (16 lanes of the quad-group)
        unsigned int iu[4];
        float en[8];
        #pragma unroll
        for (int i = 0; i < 8; ++i) {
            float s = e[i];
            s += __shfl_xor(s, 1, 16);
            s += __shfl_xor(s, 2, 16);
            s += __shfl_xor(s, 4, 16);
            s += __shfl_xor(s, 8, 16);
            en[i] = e[i] * __builtin_amdgcn_rcpf(s + 1e-6f);
        }
        #pragma unroll
        for (int ih = 0; ih < 4; ++ih)
            iu[ih] = pack2_bf16(en[2 * ih], en[2 * ih + 1]);
        const short8 ifrag = *(const short8*)iu;

        // feats A-frags: elem i = feat[idx[quad*8+i]][c=t*16+n16]
        unsigned int fu[4][4];
        if (PK) {
            #pragma unroll
            for (int ih = 0; ih < 4; ++ih) {
                const unsigned int ax = g[2 * ih].x, bx = g[2 * ih + 1].x;
                const unsigned int ay = g[2 * ih].y, by = g[2 * ih + 1].y;
                fu[0][ih] = __builtin_amdgcn_perm(bx, ax, 0x05040100u);
                fu[1][ih] = __builtin_amdgcn_perm(bx, ax, 0x07060302u);
                fu[2][ih] = __builtin_amdgcn_perm(by, ay, 0x05040100u);
                fu[3][ih] = __builtin_amdgcn_perm(by, ay, 0x07060302u);
            }
        } else {
            #pragma unroll
            for (int ih = 0; ih < 4; ++ih) {
                const float* fr0 = fbf + (size_t)idxv[2 * ih]     * CIN + n16;
                const float* fr1 = fbf + (size_t)idxv[2 * ih + 1] * CIN + n16;
                #pragma unroll
                for (int t = 0; t < 4; ++t)
                    fu[t][ih] = pack2_bf16(fr0[t * 16], fr1[t * 16]);
            }
        }

        // D[c_local][j] per m-tile t; store F[j][c] bf16 with XOR swizzle
        #pragma unroll
        for (int t = 0; t < 4; ++t) {
            const short8 ffrag = *(const short8*)(fu[t]);
            f32x4 z = {0.f, 0.f, 0.f, 0.f};
            const f32x4 dd = __builtin_amdgcn_mfma_f32_16x16x32_bf16(ffrag, ifrag, z, 0, 0, 0);
            const unsigned int lo = pack2_bf16(dd[0], dd[1]);
            const unsigned int hi = pack2_bf16(dd[2], dd[3]);
            const int off = pl * PROW + n16 * 128 +
                            ((t * 32 + quad * 8) ^ ((n16 & 7) << 4));
            uint2 v; v.x = lo; v.y = hi;
            *(uint2*)(sF + off) = v;                  // ds_write_b64
        }
    }
    __syncthreads();

    // ---------------- Phase B: wave wv owns n-tile wv, both m-tiles ----------------
    const int lm = n16;                               // point within m-tile
    f32x4 acc0 = {0.f, 0.f, 0.f, 0.f};
    f32x4 acc1 = {0.f, 0.f, 0.f, 0.f};
    const char* aBase = sF + lm * PROW;

    #pragma unroll
    for (int s = 0; s < 30; ++s) {
        const int j   = s >> 1;
        const int c0b = (s & 1) * 64 + quad * 16;
        const int off = j * 128 + (c0b ^ ((j & 7) << 4));
        const short8 a0 = *(const short8*)(aBase + off);
        const short8 a1 = *(const short8*)(aBase + 16 * PROW + off);
        const short8 bf = *(const short8*)(wfrag + ((size_t)(s * 8 + wv) * 64 + lane) * 8);
        acc0 = __builtin_amdgcn_mfma_f32_16x16x32_bf16(a0, bf, acc0, 0, 0, 0);
        acc1 = __builtin_amdgcn_mfma_f32_16x16x32_bf16(a1, bf, acc1, 0, 0, 0);
    }

    const float bsv = bias[wv * 16 + lm];
    #pragma unroll
    for (int r = 0; r < 4; ++r) {
        const int pr = quad * 4 + r;
        out[(size_t)(gp_base + pr)      * COUT + wv * 16 + lm] = acc0[r] + bsv;
        out[(size_t)(gp_base + 16 + pr) * COUT + wv * 16 + lm] = acc1[r] + bsv;
    }
}

extern "C" void kernel_launch(void* const* d_in, const int* in_sizes, int n_in,
                              void* d_out, int out_size, void* d_ws, size_t ws_size,
                              hipStream_t stream) {
    const float* qp = (const float*)d_in[0];   // query_points   [B,N,3]
    const float* sp = (const float*)d_in[1];   // support_points [B,M,3]
    const float* ft = (const float*)d_in[2];   // support_features [B,M,C_IN]
    const int*   ni = (const int*)d_in[3];     // neighbor_idx   [B,N,K]
    const float* kp = (const float*)d_in[4];   // kernel_points  [KS,3]
    const float* wg = (const float*)d_in[5];   // weights        [KS,C_IN,C_OUT]
    const float* bs = (const float*)d_in[6];   // bias           [C_OUT]
    float* o = (float*)d_out;                  // [B,N,C_OUT] fp32

    unsigned short* wfrag = (unsigned short*)d_ws;
    unsigned int*   fpk   = (unsigned int*)((char*)d_ws + WF_BYTES);
    float4*         sp4   = (float4*)((char*)d_ws + WF_BYTES + FP_BYTES);
    const int full = (ws_size >= (size_t)(WF_BYTES + FP_BYTES + SP4_BYTES)) ? 1 : 0;

    const int prep_blocks = full ? (60 + 128 + 4096) : 60;
    hipLaunchKernelGGL(prep_kernel, dim3(prep_blocks), dim3(256), 0, stream,
                       wg, ft, sp, wfrag, fpk, sp4, full);

    if (full) {
        hipLaunchKernelGGL((kpconv_mfma<true>), dim3((2 * NB) / TP), dim3(512), 0, stream,
                           qp, sp, ft, fpk, sp4, ni, kp, wfrag, bs, o);
    } else {
        hipLaunchKernelGGL((kpconv_mfma<false>), dim3((2 * NB) / TP), dim3(512), 0, stream,
                           qp, sp, ft, fpk, sp4, ni, kp, wfrag, bs, o);
    }
}